// Round 13
// baseline (197.368 us; speedup 1.0000x reference)
//
#include <hip/hip_runtime.h>
#include <hip/hip_bf16.h>
#include <cstddef>

// G=1024 x 64 nodes, V=32, H=128, DIN=128, DOUT=10, E=1048576.
// R9 (2nd resubmit after infra timeouts): R7 base (best: 44.5us) + 2D wave
//     tiling on weight GEMMs. R8's barrier cuts regressed (+6us) -> reverted.
//     Theory: fused_graph is LDS-read-issue bound (~96 ds_read_b128/wave at
//     ~12cyc inherent 2-lane aliasing; every wave read the FULL A-tile).
//     Waves now tile output 2D: (fo = wv&3) 32-fout slice x (nh = wv>>2)
//     32-row half -> A/B tile reads halve on P1/P2/P4/P5/P8/P9. Weight frags
//     32-wide in regs (Bp/Bn[8]). MFMA count unchanged. P3/P6/P7/tail = R7.
//     vemb prefetch moved JIT into P4 (stay under 128-VGPR (512,2) budget).

#define EDGES 1048576
#define CAP 2048   // per-graph sorted-edge segment capacity
#define SR 136     // row stride (bf16) of row-major [node][feat] LDS tiles
#define ST 72      // row stride (bf16) of transposed [feat][node] LDS tiles

typedef __attribute__((ext_vector_type(8))) short short8;
typedef __attribute__((ext_vector_type(4))) float f32x4;
typedef __hip_bfloat16 bf;
struct __align__(8) bf4 { bf v[4]; };

// ---------------- s1: per-block histogram over graph bins ----------------
__global__ __launch_bounds__(256) void edge_hist(const int* __restrict__ ei,
                                                 unsigned* __restrict__ H)
{
    __shared__ unsigned lh[1024];
    int tid = threadIdx.x, b = blockIdx.x;
    for (int t = tid; t < 1024; t += 256) lh[t] = 0;
    __syncthreads();
    int base = b * 4096;
#pragma unroll 4
    for (int t = 0; t < 16; ++t) {
        int s = ei[base + t * 256 + tid];
        atomicAdd(&lh[s >> 6], 1u);      // LDS atomic
    }
    __syncthreads();
    for (int t = tid; t < 1024; t += 256) H[b * 1024 + t] = lh[t];
}

// ------- s2: wave-parallel cross-block scan (+ fused weight conversion) -------
__global__ __launch_bounds__(256) void scan_conv(
    unsigned* __restrict__ H, unsigned* __restrict__ Tot,
    const float* __restrict__ w0, const float* __restrict__ w1,
    const float* __restrict__ w2, const float* __restrict__ w3,
    const float* __restrict__ w4, const float* __restrict__ w5,
    bf* __restrict__ outw)
{
    int b = blockIdx.x;
    if (b < 256) {
        int wv = threadIdx.x >> 6, lane = threadIdx.x & 63;
        int g = b * 4 + wv;
        unsigned v[4];
#pragma unroll
        for (int c = 0; c < 4; ++c) v[c] = H[(c * 64 + lane) * 1024 + g];
        unsigned run = 0;
#pragma unroll
        for (int c = 0; c < 4; ++c) {
            unsigned s = v[c];
            unsigned incl = s;
#pragma unroll
            for (int d = 1; d < 64; d <<= 1) {
                unsigned t = __shfl_up(incl, d);
                if (lane >= d) incl += t;
            }
            H[(c * 64 + lane) * 1024 + g] = run + (incl - s);
            run += __shfl(incl, 63);
        }
        if (lane == 0) Tot[g] = run;
    } else {
        int idx = (b - 256) * 256 + threadIdx.x;   // n*128+k
        int n = idx >> 7, k = idx & 127;
        int off = (((n >> 4) * 4 + (k >> 5)) * 512) + (n & 15) * 32 + (k & 31);
        const float* srcs[6] = { w0, w1, w2, w3, w4, w5 };
#pragma unroll
        for (int m = 0; m < 6; ++m) {
            float vv = (m == 3) ? srcs[m][n * 128 + k] : srcs[m][k * 128 + n];
            outw[m * 16384 + off] = __float2bfloat16(vv);
        }
    }
}

// ---------------- s3: scatter edges into fixed per-graph segments ----------------
__global__ __launch_bounds__(256) void edge_scatter(const int* __restrict__ ei,
                                                    const unsigned* __restrict__ H,
                                                    unsigned short* __restrict__ sorted)
{
    __shared__ unsigned lh[1024];
    __shared__ unsigned hrow[1024];
    int tid = threadIdx.x, b = blockIdx.x;
    for (int t = tid; t < 1024; t += 256) { lh[t] = 0; hrow[t] = H[b * 1024 + t]; }
    __syncthreads();
    int base = b * 4096;
    for (int t = 0; t < 16; ++t) {
        int e = base + t * 256 + tid;
        int s = ei[e], d = ei[EDGES + e];
        int g = s >> 6;
        unsigned r = atomicAdd(&lh[g], 1u);          // LDS atomic rank
        unsigned o = hrow[g] + r;
        if (o < (unsigned)CAP)
            sorted[(unsigned)g * CAP + o] = (unsigned short)(((d & 63) << 6) | (s & 63));
    }
}

// weight-frag prefetch for a 32-fout slice fo: 8 frags (f2=0..1 x ks=0..3)
__device__ __forceinline__ void loadB2(const bf* __restrict__ gW, int fo, int l15,
                                       int kofs, short8* B)
{
#pragma unroll
    for (int f2 = 0; f2 < 2; ++f2)
#pragma unroll
        for (int ks = 0; ks < 4; ++ks)
            B[f2 * 4 + ks] = *(const short8*)(gW + (((fo * 2 + f2) * 4 + ks) * 512)
                                              + l15 * 32 + kofs);
}

// new-order 2D: A = weight frags (32-fout slice), B = LDS rows (NT 16-row groups)
// D[fout(q*4+r)][node(l15)] ; acc[f2][nt]
template<int NT, int SB>
__device__ __forceinline__ void mmaBA2(const bf* sB, int rowB, int l15, int kofs,
                                       const short8* A, f32x4 (*acc)[NT])
{
#pragma unroll
    for (int ks = 0; ks < 4; ++ks) {
        short8 b[NT];
#pragma unroll
        for (int nt = 0; nt < NT; ++nt)
            b[nt] = *(const short8*)(sB + (rowB + nt * 16 + l15) * SB + ks * 32 + kofs);
#pragma unroll
        for (int f2 = 0; f2 < 2; ++f2)
#pragma unroll
            for (int nt = 0; nt < NT; ++nt)
                acc[f2][nt] = __builtin_amdgcn_mfma_f32_16x16x32_bf16(
                    A[f2 * 4 + ks], b[nt], acc[f2][nt], 0, 0, 0);
    }
}

// old-order 2D: A = LDS rows (MT 16-row groups), B = weight frags (32-fout slice)
// D[node(q*4+r)][fout(l15)] ; acc[m][f2]
template<int MT, int SA>
__device__ __forceinline__ void mmaAB2(const bf* sA, int rowA, int l15, int kofs,
                                       const short8* B, f32x4 (*acc)[2])
{
#pragma unroll
    for (int ks = 0; ks < 4; ++ks) {
        short8 a[MT];
#pragma unroll
        for (int m = 0; m < MT; ++m)
            a[m] = *(const short8*)(sA + (rowA + m * 16 + l15) * SA + ks * 32 + kofs);
#pragma unroll
        for (int m = 0; m < MT; ++m)
#pragma unroll
            for (int f2 = 0; f2 < 2; ++f2)
                acc[m][f2] = __builtin_amdgcn_mfma_f32_16x16x32_bf16(
                    a[m], B[f2 * 4 + ks], acc[m][f2], 0, 0, 0);
    }
}

// both operands from LDS (P3)
template<int MT, int KS, int SA, int SB>
__device__ __forceinline__ void mmaABlds(const bf* sA, int rowA, const bf* sB, int rowB,
                                         int l15, int kofs, f32x4* acc)
{
#pragma unroll
    for (int ks = 0; ks < KS; ++ks) {
        short8 bb = *(const short8*)(sB + (rowB + l15) * SB + ks * 32 + kofs);
        short8 a[MT];
#pragma unroll
        for (int m = 0; m < MT; ++m)
            a[m] = *(const short8*)(sA + (rowA + m * 16 + l15) * SA + ks * 32 + kofs);
#pragma unroll
        for (int m = 0; m < MT; ++m)
            acc[m] = __builtin_amdgcn_mfma_f32_16x16x32_bf16(a[m], bb, acc[m], 0, 0, 0);
    }
}

__global__ __launch_bounds__(512, 2) void fused_graph(
    const float* __restrict__ x, const float* __restrict__ edge_w,
    const float* __restrict__ vemb, const bf* __restrict__ gWb,
    const float* __restrict__ b_emb,  const float* __restrict__ b_gcn,
    const float* __restrict__ aff_b1, const float* __restrict__ aff_b2,
    const float* __restrict__ vn_b1,  const float* __restrict__ vn_b2,
    const float* __restrict__ mlp_W1, const float* __restrict__ mlp_b1,
    const float* __restrict__ mlp_W2, const float* __restrict__ mlp_b2,
    const unsigned short* __restrict__ sorted,
    const unsigned* __restrict__ Tot,
    float* __restrict__ out)
{
    __shared__ __align__(16) bf sRM1[64 * SR];   // 17,408 B
    __shared__ __align__(16) bf sRM2[64 * SR];   // 17,408 B (also fp32 sF tail)
    __shared__ __align__(16) bf sT1 [128 * ST];  // 18,432 B (cnt / hws^T / S+ewnT)
    __shared__ __align__(16) bf sT2 [128 * ST];  // 18,432 B (h_gcn^T / vn2^T fp32)
    __shared__ __align__(16) bf sAdj[64 * ST];   //  9,216 B (adj / vemb / P6 partials)
    __shared__ float sInv[64];
    __shared__ float sBatt[32];
    // total 81,280 B -> 2 blocks/CU

    unsigned* cnt = (unsigned*)sT1;        // 1024 u32 words (u8-packed counts)
    bf* sVemb = sAdj;                      // 32 x SR after P3 (4352 bf)
    float* sPart = (float*)(sAdj + 4352);  // 128 fp32 (P6 row partials; sAdj tail)
    bf* sS    = sT1;                       // 32 x SR (S[v][o])
    bf* sEwnT = sT1 + 4608;                // 32 x ST (ewn^T[v][node])
    float* sT2f = (float*)sT2;             // 128 x 34 fp32

    const int tid = threadIdx.x;
    const int g = blockIdx.x;
    const int wv = tid >> 6;               // 0..7
    const int lane = tid & 63;
    const int l15 = lane & 15;
    const int q = lane >> 4;
    const int kofs = q * 8;
    const int c = wv * 16 + l15;           // 1D phases' (P3/P7) output column
    const int fq = wv * 16 + q * 4;        // P7 fout base
    const int fo = wv & 3;                 // 2D phases: 32-fout slice
    const int nh = wv >> 2;                // 2D phases: 32-row half
    const int fb = fo * 32;                // fout slice base

    // ---- entry prefetches (global->VGPR; independent of all barriers) ----
    short8 Bp[8], Bn[8];
    loadB2(gWb, fo, l15, kofs, Bp);                // W_emb   (P1)
    loadB2(gWb + 16384, fo, l15, kofs, Bn);        // W_gcn   (P2)
    float4 xreg[4];
    const float4* gx = (const float4*)(x + (size_t)g * 8192);
#pragma unroll
    for (int t = 0; t < 4; ++t) xreg[t] = gx[tid + t * 512];
    // P6 tile: rows (wv&3)*16 + q*4 + r, v = (wv>>2)*16 + l15
    const int p6row = fo * 16;
    const int p6v   = nh * 16 + l15;
    float ewreg[4];
#pragma unroll
    for (int r = 0; r < 4; ++r)
        ewreg[r] = edge_w[(size_t)g * 2048 + (p6row + q * 4 + r) * 32 + p6v];
    float bias_g = b_gcn[c];
    unsigned ecnt = min(Tot[g], (unsigned)CAP);
    unsigned ebase = (unsigned)g * CAP;

    // ---- P0a: zero counts ----
#pragma unroll
    for (int t = 0; t < 2; ++t) cnt[tid * 2 + t] = 0u;
    __syncthreads();
    // ---- P0b: build counts (LDS atomics) + stage x ----
    for (unsigned i = tid; i < ecnt; i += 512) {
        unsigned w = sorted[ebase + i];
        unsigned d = w >> 6, s = w & 63u;
        atomicAdd(&cnt[d * 16 + (s >> 2)], 1u << ((s & 3u) * 8));
    }
#pragma unroll
    for (int t = 0; t < 4; ++t) {
        int i = tid + t * 512;
        int row = i >> 5, c4 = i & 31;
        float4 w = xreg[t];
        bf4 tt;
        tt.v[0] = __float2bfloat16(w.x); tt.v[1] = __float2bfloat16(w.y);
        tt.v[2] = __float2bfloat16(w.z); tt.v[3] = __float2bfloat16(w.w);
        *(bf4*)(sRM1 + row * SR + c4 * 4) = tt;
    }
    __syncthreads();
    // ---- P0c: counts -> bf16 adjacency (+self-loop) + inv=rsqrt(deg) ----
    {
        int r = tid >> 3, q8 = tid & 7;
        float rs = 0.f;
#pragma unroll
        for (int t = 0; t < 2; ++t) {
            unsigned wd = cnt[r * 16 + q8 * 2 + t];
#pragma unroll
            for (int j = 0; j < 4; ++j) {
                int s = (q8 * 2 + t) * 4 + j;
                float v = (float)((wd >> (j * 8)) & 255u) + (s == r ? 1.f : 0.f);
                rs += v;
                sAdj[r * ST + s] = __float2bfloat16(v);
            }
        }
        rs += __shfl_xor(rs, 1);
        rs += __shfl_xor(rs, 2);
        rs += __shfl_xor(rs, 4);
        if (q8 == 0) sInv[r] = rsqrtf(rs);
    }
    __syncthreads();

    // ---- P1: h = x @ W_emb + b_emb -> sRM2 RM (2D: fo-slice x nh-half) ----
    {
        f32x4 acc[2][2] = {};
        mmaBA2<2, SR>(sRM1, nh * 32, l15, kofs, Bp, acc);
        loadB2(gWb + 2 * 16384, fo, l15, kofs, Bp);   // aff_W1 (P4)
#pragma unroll
        for (int f2 = 0; f2 < 2; ++f2) {
            f32x4 b4 = *(const f32x4*)(b_emb + fb + f2 * 16 + q * 4);
#pragma unroll
            for (int nt = 0; nt < 2; ++nt) {
                bf4 tv;
#pragma unroll
                for (int r = 0; r < 4; ++r)
                    tv.v[r] = __float2bfloat16(acc[f2][nt][r] + b4[r]);
                *(bf4*)(sRM2 + (nh * 32 + nt * 16 + l15) * SR + fb + f2 * 16 + q * 4) = tv;
            }
        }
    }
    __syncthreads();

    // ---- P2: hws^T = (h @ W_gcn) * inv[row] -> sT1 T (2D, packed) ----
    {
        f32x4 acc[2][2] = {};
        mmaAB2<2, SR>(sRM2, nh * 32, l15, kofs, Bn, acc);
        loadB2(gWb + 3 * 16384, fo, l15, kofs, Bn);   // aff_W2 (P5)
#pragma unroll
        for (int m = 0; m < 2; ++m) {
            f32x4 iv = *(const f32x4*)(sInv + nh * 32 + m * 16 + q * 4);
#pragma unroll
            for (int f2 = 0; f2 < 2; ++f2) {
                bf4 tv;
#pragma unroll
                for (int r = 0; r < 4; ++r)
                    tv.v[r] = __float2bfloat16(acc[m][f2][r] * iv[r]);
                *(bf4*)(sT1 + (fb + f2 * 16 + l15) * ST + nh * 32 + m * 16 + q * 4) = tv;
            }
        }
    }
    __syncthreads();

    // ---- P3: h_gcn = relu(inv[d]*(A' @ hws) + b_gcn) -> sRM1 RM + sT2 T (1D) ----
    {
        f32x4 acc[4] = {};
        mmaABlds<4, 2, ST, ST>(sAdj, 0, sT1, wv * 16, l15, kofs, acc);
#pragma unroll
        for (int m = 0; m < 4; ++m) {
            bf4 tv;
#pragma unroll
            for (int r = 0; r < 4; ++r) {
                float v = fmaxf(acc[m][r] * sInv[m * 16 + q * 4 + r] + bias_g, 0.f);
                sRM1[(m * 16 + q * 4 + r) * SR + c] = __float2bfloat16(v);
                tv.v[r] = __float2bfloat16(v);
            }
            *(bf4*)(sT2 + c * ST + m * 16 + q * 4) = tv;
        }
    }
    __syncthreads();

    // ---- P4: affh = relu(h_gcn @ aff_W1 + aff_b1) -> sRM2 RM (2D) ; vemb -> LDS ----
    {
        float4 vreg[2];
        const float4* gv = (const float4*)(vemb + (size_t)g * 4096);
#pragma unroll
        for (int t = 0; t < 2; ++t) vreg[t] = gv[tid + t * 512];
        f32x4 acc[2][2] = {};
        mmaBA2<2, SR>(sRM1, nh * 32, l15, kofs, Bp, acc);
        loadB2(gWb + 4 * 16384, fo, l15, kofs, Bp);   // vn_W1 (P8)
#pragma unroll
        for (int t = 0; t < 2; ++t) {
            int i = tid + t * 512;
            int v = i >> 5, o4 = i & 31;
            float4 w = vreg[t];
            bf4 tt;
            tt.v[0] = __float2bfloat16(w.x); tt.v[1] = __float2bfloat16(w.y);
            tt.v[2] = __float2bfloat16(w.z); tt.v[3] = __float2bfloat16(w.w);
            *(bf4*)(sVemb + v * SR + o4 * 4) = tt;
        }
#pragma unroll
        for (int f2 = 0; f2 < 2; ++f2) {
            f32x4 b4 = *(const f32x4*)(aff_b1 + fb + f2 * 16 + q * 4);
#pragma unroll
            for (int nt = 0; nt < 2; ++nt) {
                bf4 tv;
#pragma unroll
                for (int r = 0; r < 4; ++r)
                    tv.v[r] = __float2bfloat16(fmaxf(acc[f2][nt][r] + b4[r], 0.f));
                *(bf4*)(sRM2 + (nh * 32 + nt * 16 + l15) * SR + fb + f2 * 16 + q * 4) = tv;
            }
        }
    }
    __syncthreads();

    // ---- P5: S[v][o] = sum_j vemb[v][j]*aff_W2[o][j] -> sS (2D: fo x vh) ; batt ----
    {
        f32x4 acc[2][1] = {};
        mmaBA2<1, SR>(sVemb, nh * 16, l15, kofs, Bn, acc);
        loadB2(gWb + 5 * 16384, fo, l15, kofs, Bn);   // vn_W2 (P9)
#pragma unroll
        for (int f2 = 0; f2 < 2; ++f2) {
            bf4 tv;
#pragma unroll
            for (int r = 0; r < 4; ++r) tv.v[r] = __float2bfloat16(acc[f2][0][r]);
            *(bf4*)(sS + (nh * 16 + l15) * SR + fb + f2 * 16 + q * 4) = tv;
        }
        if (tid < 256) {
            int v = tid >> 3, sg = tid & 7;
            float s = 0.f;
            const bf* pv = sVemb + v * SR + sg * 16;
            const float* pb = aff_b2 + sg * 16;
#pragma unroll
            for (int o = 0; o < 16; ++o) s += pb[o] * __bfloat162float(pv[o]);
            s += __shfl_xor(s, 1); s += __shfl_xor(s, 2); s += __shfl_xor(s, 4);
            if (sg == 0) sBatt[v] = s;
        }
    }
    __syncthreads();

    // ---- P6: att -> sigmoid gate -> row-normalize -> sEwnT[v][node] (R7 form) ----
    {
        f32x4 acc = {};
#pragma unroll
        for (int ks = 0; ks < 4; ++ks) {
            short8 bb = *(const short8*)(sS + (nh * 16 + l15) * SR + ks * 32 + kofs);
            short8 a  = *(const short8*)(sRM2 + (p6row + l15) * SR + ks * 32 + kofs);
            acc = __builtin_amdgcn_mfma_f32_16x16x32_bf16(a, bb, acc, 0, 0, 0);
        }
        const float sc = 0.08838834764831845f;   // 1/sqrt(128)
        float bt = sBatt[p6v];
        float e[4];
#pragma unroll
        for (int r = 0; r < 4; ++r) {
            float att = (acc[r] + bt) * sc;
            e[r] = ewreg[r] * (1.f + 1.f / (1.f + __expf(-att)));
            float rs = e[r];
            rs += __shfl_xor(rs, 1); rs += __shfl_xor(rs, 2);
            rs += __shfl_xor(rs, 4); rs += __shfl_xor(rs, 8);
            if (l15 == 0) sPart[nh * 64 + p6row + q * 4 + r] = rs;
        }
        __syncthreads();
        bf4 tv;
#pragma unroll
        for (int r = 0; r < 4; ++r) {
            float rs = sPart[p6row + q * 4 + r] + sPart[64 + p6row + q * 4 + r];
            tv.v[r] = __float2bfloat16(e[r] / rs);
        }
        *(bf4*)(sEwnT + (nh * 16 + l15) * ST + p6row + q * 4) = tv;
    }
    __syncthreads();

    // ---- P7: vn = ewn^T @ h_gcn -> sRM1 rows 0..31 (1D, packed) ----
    {
        f32x4 acc[2] = {};
#pragma unroll
        for (int ks = 0; ks < 2; ++ks) {
            short8 af = *(const short8*)(sT2 + (wv * 16 + l15) * ST + ks * 32 + kofs);
            short8 b0 = *(const short8*)(sEwnT + l15 * ST + ks * 32 + kofs);
            short8 b1 = *(const short8*)(sEwnT + (16 + l15) * ST + ks * 32 + kofs);
            acc[0] = __builtin_amdgcn_mfma_f32_16x16x32_bf16(af, b0, acc[0], 0, 0, 0);
            acc[1] = __builtin_amdgcn_mfma_f32_16x16x32_bf16(af, b1, acc[1], 0, 0, 0);
        }
#pragma unroll
        for (int nt = 0; nt < 2; ++nt) {
            bf4 tv;
#pragma unroll
            for (int r = 0; r < 4; ++r) tv.v[r] = __float2bfloat16(acc[nt][r]);
            *(bf4*)(sRM1 + (nt * 16 + l15) * SR + fq) = tv;
        }
    }
    __syncthreads();

    // ---- P8: z1 = relu(vn @ vn_W1 + vn_b1) -> sRM1 rows 32..63 (2D) ----
    {
        f32x4 acc[2][1] = {};
        mmaBA2<1, SR>(sRM1, nh * 16, l15, kofs, Bp, acc);
#pragma unroll
        for (int f2 = 0; f2 < 2; ++f2) {
            f32x4 b4 = *(const f32x4*)(vn_b1 + fb + f2 * 16 + q * 4);
            bf4 tv;
#pragma unroll
            for (int r = 0; r < 4; ++r)
                tv.v[r] = __float2bfloat16(fmaxf(acc[f2][0][r] + b4[r], 0.f));
            *(bf4*)(sRM1 + (32 + nh * 16 + l15) * SR + fb + f2 * 16 + q * 4) = tv;
        }
    }
    __syncthreads();

    // ---- P9: vn2 = z1 @ vn_W2 + vn_b2 -> sT2f[feat][v] fp32 (2D) ----
    {
        f32x4 acc[1][2] = {};
        mmaAB2<1, SR>(sRM1 + 32 * SR, nh * 16, l15, kofs, Bn, acc);
#pragma unroll
        for (int f2 = 0; f2 < 2; ++f2) {
            float bv2 = vn_b2[fb + f2 * 16 + l15];
#pragma unroll
            for (int r = 0; r < 4; ++r)
                sT2f[(fb + f2 * 16 + l15) * 34 + nh * 16 + q * 4 + r] =
                    acc[0][f2][r] + bv2;
        }
    }
    __syncthreads();

    // ---- P10: gf = mean over V -> LDS (sRM2 reused as fp32 scratch) ----
    float* sF = (float*)sRM2;    // [0:128)=gf, [128:640)=partials, [640:768)=z1
    if (tid < 128) {
        float s = 0.f;
#pragma unroll
        for (int v = 0; v < 32; ++v) s += sT2f[tid * 34 + v];
        sF[tid] = s * 0.03125f;
    }
    __syncthreads();

    // ---- P11: z1 = relu(gf @ mlp_W1 + mlp_b1) (fp32, split-K over 4) ----
    {
        int o = tid & 127, hh = tid >> 7;            // hh = 0..3
        const float* w = mlp_W1 + (size_t)(hh * 32) * 128 + o;
        float a = 0.f;
#pragma unroll 8
        for (int k = 0; k < 32; ++k) a = fmaf(sF[hh * 32 + k], w[k * 128], a);
        sF[128 + hh * 128 + o] = a;
    }
    __syncthreads();
    if (tid < 128)
        sF[640 + tid] = fmaxf(sF[128 + tid] + sF[256 + tid] + sF[384 + tid]
                              + sF[512 + tid] + mlp_b1[tid], 0.f);
    __syncthreads();

    // ---- P12: out = z1 @ mlp_W2 + mlp_b2 ----
    if (tid < 80) {
        int oo = tid >> 3, jg = tid & 7;
        float p = 0.f;
#pragma unroll
        for (int t2 = 0; t2 < 16; ++t2) {
            int j = jg * 16 + t2;
            p = fmaf(sF[640 + j], mlp_W2[j * 10 + oo], p);
        }
        p += __shfl_xor(p, 1); p += __shfl_xor(p, 2); p += __shfl_xor(p, 4);
        if (jg == 0) out[g * 10 + oo] = p + mlp_b2[oo];
    }
}

extern "C" void kernel_launch(void* const* d_in, const int* in_sizes, int n_in,
                              void* d_out, int out_size, void* d_ws, size_t ws_size,
                              hipStream_t stream)
{
    const float* x       = (const float*)d_in[0];
    const int*   ei      = (const int*)  d_in[1];
    // d_in[2] = batch (unused)
    const float* edge_w  = (const float*)d_in[3];
    const float* vemb    = (const float*)d_in[4];
    const float* W_emb   = (const float*)d_in[5];
    const float* b_emb   = (const float*)d_in[6];
    const float* W_gcn   = (const float*)d_in[7];
    const float* b_gcn   = (const float*)d_in[8];
    const float* aff_W1  = (const float*)d_in[9];
    const float* aff_b1  = (const float*)d_in[10];
    const float* aff_W2  = (const float*)d_in[11];
    const float* aff_b2  = (const float*)d_in[12];
    const float* vn_W1   = (const float*)d_in[13];
    const float* vn_b1   = (const float*)d_in[14];
    const float* vn_W2   = (const float*)d_in[15];
    const float* vn_b2   = (const float*)d_in[16];
    const float* mlp_W1  = (const float*)d_in[17];
    const float* mlp_b1  = (const float*)d_in[18];
    const float* mlp_W2  = (const float*)d_in[19];
    const float* mlp_b2  = (const float*)d_in[20];

    char* ws = (char*)d_ws;
    unsigned short* sorted = (unsigned short*)ws;               // 4 MB (1024*2048 u16)
    unsigned* H    = (unsigned*)(ws + (4u << 20));              // 1 MB (256*1024 u32)
    unsigned* Tot  = (unsigned*)(ws + (5u << 20));              // 4 KB
    bf*       gWb  = (bf*)      (ws + (5u << 20) + 65536);      // 192 KB

    edge_hist  <<<dim3(256), dim3(256), 0, stream>>>(ei, H);
    scan_conv  <<<dim3(320), dim3(256), 0, stream>>>(
        H, Tot, W_emb, W_gcn, aff_W1, aff_W2, vn_W1, vn_W2, gWb);
    edge_scatter<<<dim3(256),dim3(256), 0, stream>>>(ei, H, sorted);
    fused_graph<<<dim3(1024), dim3(512), 0, stream>>>(
        x, edge_w, vemb, gWb, b_emb, b_gcn, aff_b1, aff_b2,
        vn_b1, vn_b2, mlp_W1, mlp_b1, mlp_W2, mlp_b2,
        sorted, Tot, (float*)d_out);
}

// Round 15
// 181.329 us; speedup vs baseline: 1.0884x; 1.0884x over previous
//
#include <hip/hip_runtime.h>
#include <hip/hip_bf16.h>
#include <cstddef>

// G=1024 x 64 nodes, V=32, H=128, DIN=128, DOUT=10, E=1048576.
// R10 (resubmit after infra timeout): exact R7 revert (best measured:
//      42.5-46.6us, VGPR 64, no spills) + ONE clean change: P0c (adjacency
//      decode + rsqrt; VALU on cnt/sAdj/sInv) merged into P1's phase (MFMA on
//      sRM1->sRM2; disjoint LDS). sInv first consumed in P2, one barrier
//      later -> safe. -1 barrier, P0c VALU overlaps P1 MFMA latency, no
//      added work/registers.
//      Falsified: occupancy (R5/R7), barrier-count (R8), LDS-volume (R9).

#define EDGES 1048576
#define CAP 2048   // per-graph sorted-edge segment capacity
#define SR 136     // row stride (bf16) of row-major [node][feat] LDS tiles
#define ST 72      // row stride (bf16) of transposed [feat][node] LDS tiles

typedef __attribute__((ext_vector_type(8))) short short8;
typedef __attribute__((ext_vector_type(4))) float f32x4;
typedef __hip_bfloat16 bf;
struct __align__(8) bf4 { bf v[4]; };

// ---------------- s1: per-block histogram over graph bins ----------------
__global__ __launch_bounds__(256) void edge_hist(const int* __restrict__ ei,
                                                 unsigned* __restrict__ H)
{
    __shared__ unsigned lh[1024];
    int tid = threadIdx.x, b = blockIdx.x;
    for (int t = tid; t < 1024; t += 256) lh[t] = 0;
    __syncthreads();
    int base = b * 4096;
#pragma unroll 4
    for (int t = 0; t < 16; ++t) {
        int s = ei[base + t * 256 + tid];
        atomicAdd(&lh[s >> 6], 1u);      // LDS atomic
    }
    __syncthreads();
    for (int t = tid; t < 1024; t += 256) H[b * 1024 + t] = lh[t];
}

// ------- s2: wave-parallel cross-block scan (+ fused weight conversion) -------
__global__ __launch_bounds__(256) void scan_conv(
    unsigned* __restrict__ H, unsigned* __restrict__ Tot,
    const float* __restrict__ w0, const float* __restrict__ w1,
    const float* __restrict__ w2, const float* __restrict__ w3,
    const float* __restrict__ w4, const float* __restrict__ w5,
    bf* __restrict__ outw)
{
    int b = blockIdx.x;
    if (b < 256) {
        int wv = threadIdx.x >> 6, lane = threadIdx.x & 63;
        int g = b * 4 + wv;
        unsigned v[4];
#pragma unroll
        for (int c = 0; c < 4; ++c) v[c] = H[(c * 64 + lane) * 1024 + g];
        unsigned run = 0;
#pragma unroll
        for (int c = 0; c < 4; ++c) {
            unsigned s = v[c];
            unsigned incl = s;
#pragma unroll
            for (int d = 1; d < 64; d <<= 1) {
                unsigned t = __shfl_up(incl, d);
                if (lane >= d) incl += t;
            }
            H[(c * 64 + lane) * 1024 + g] = run + (incl - s);
            run += __shfl(incl, 63);
        }
        if (lane == 0) Tot[g] = run;
    } else {
        int idx = (b - 256) * 256 + threadIdx.x;   // n*128+k
        int n = idx >> 7, k = idx & 127;
        int off = (((n >> 4) * 4 + (k >> 5)) * 512) + (n & 15) * 32 + (k & 31);
        const float* srcs[6] = { w0, w1, w2, w3, w4, w5 };
#pragma unroll
        for (int m = 0; m < 6; ++m) {
            float vv = (m == 3) ? srcs[m][n * 128 + k] : srcs[m][k * 128 + n];
            outw[m * 16384 + off] = __float2bfloat16(vv);
        }
    }
}

// ---------------- s3: scatter edges into fixed per-graph segments ----------------
__global__ __launch_bounds__(256) void edge_scatter(const int* __restrict__ ei,
                                                    const unsigned* __restrict__ H,
                                                    unsigned short* __restrict__ sorted)
{
    __shared__ unsigned lh[1024];
    __shared__ unsigned hrow[1024];
    int tid = threadIdx.x, b = blockIdx.x;
    for (int t = tid; t < 1024; t += 256) { lh[t] = 0; hrow[t] = H[b * 1024 + t]; }
    __syncthreads();
    int base = b * 4096;
    for (int t = 0; t < 16; ++t) {
        int e = base + t * 256 + tid;
        int s = ei[e], d = ei[EDGES + e];
        int g = s >> 6;
        unsigned r = atomicAdd(&lh[g], 1u);          // LDS atomic rank
        unsigned o = hrow[g] + r;
        if (o < (unsigned)CAP)
            sorted[(unsigned)g * CAP + o] = (unsigned short)(((d & 63) << 6) | (s & 63));
    }
}

// B-prefetch: 4 frags (ks=0..3) for this wave's 16-row slice; 1KB contiguous each
__device__ __forceinline__ void loadB(const bf* __restrict__ gW, int wv, int l15,
                                      int kofs, short8* B)
{
#pragma unroll
    for (int ks = 0; ks < 4; ++ks)
        B[ks] = *(const short8*)(gW + (wv * 4 + ks) * 512 + l15 * 32 + kofs);
}

// old-order: A = LDS tile rows, B = weight frags in regs -> D[Arow][Wrow]
template<int MT, int KS, int SA>
__device__ __forceinline__ void mmaAB(const bf* sA, int rowA, int l15, int kofs,
                                      const short8* B, f32x4* acc)
{
#pragma unroll
    for (int ks = 0; ks < KS; ++ks) {
        short8 a[MT];
#pragma unroll
        for (int m = 0; m < MT; ++m)
            a[m] = *(const short8*)(sA + (rowA + m * 16 + l15) * SA + ks * 32 + kofs);
#pragma unroll
        for (int m = 0; m < MT; ++m)
            acc[m] = __builtin_amdgcn_mfma_f32_16x16x32_bf16(a[m], B[ks], acc[m], 0, 0, 0);
    }
}

// new-order: A = weight frags in regs, B = LDS tile rows -> D[Wrow][Brow]
// (fragment layouts are lane-symmetric; packed bf4 epilogue along D-rows)
template<int NT, int KS, int SB>
__device__ __forceinline__ void mmaBA(const bf* sB, int rowB, int l15, int kofs,
                                      const short8* A, f32x4* acc)
{
#pragma unroll
    for (int ks = 0; ks < KS; ++ks) {
        short8 b[NT];
#pragma unroll
        for (int nt = 0; nt < NT; ++nt)
            b[nt] = *(const short8*)(sB + (rowB + nt * 16 + l15) * SB + ks * 32 + kofs);
#pragma unroll
        for (int nt = 0; nt < NT; ++nt)
            acc[nt] = __builtin_amdgcn_mfma_f32_16x16x32_bf16(A[ks], b[nt], acc[nt], 0, 0, 0);
    }
}

// both operands from LDS (A rows stride ST, B rows stride ST)
template<int MT, int KS, int SA, int SB>
__device__ __forceinline__ void mmaABlds(const bf* sA, int rowA, const bf* sB, int rowB,
                                         int l15, int kofs, f32x4* acc)
{
#pragma unroll
    for (int ks = 0; ks < KS; ++ks) {
        short8 bb = *(const short8*)(sB + (rowB + l15) * SB + ks * 32 + kofs);
        short8 a[MT];
#pragma unroll
        for (int m = 0; m < MT; ++m)
            a[m] = *(const short8*)(sA + (rowA + m * 16 + l15) * SA + ks * 32 + kofs);
#pragma unroll
        for (int m = 0; m < MT; ++m)
            acc[m] = __builtin_amdgcn_mfma_f32_16x16x32_bf16(a[m], bb, acc[m], 0, 0, 0);
    }
}

__global__ __launch_bounds__(512, 2) void fused_graph(
    const float* __restrict__ x, const float* __restrict__ edge_w,
    const float* __restrict__ vemb, const bf* __restrict__ gWb,
    const float* __restrict__ b_emb,  const float* __restrict__ b_gcn,
    const float* __restrict__ aff_b1, const float* __restrict__ aff_b2,
    const float* __restrict__ vn_b1,  const float* __restrict__ vn_b2,
    const float* __restrict__ mlp_W1, const float* __restrict__ mlp_b1,
    const float* __restrict__ mlp_W2, const float* __restrict__ mlp_b2,
    const unsigned short* __restrict__ sorted,
    const unsigned* __restrict__ Tot,
    float* __restrict__ out)
{
    __shared__ __align__(16) bf sRM1[64 * SR];   // 17,408 B
    __shared__ __align__(16) bf sRM2[64 * SR];   // 17,408 B (also fp32 sF tail)
    __shared__ __align__(16) bf sT1 [128 * ST];  // 18,432 B (cnt / hws^T / S+ewnT)
    __shared__ __align__(16) bf sT2 [128 * ST];  // 18,432 B (h_gcn^T / vn2^T fp32)
    __shared__ __align__(16) bf sAdj[64 * ST];   //  9,216 B (adj / vemb / P6 partials)
    __shared__ float sInv[64];
    __shared__ float sBatt[32];
    // total 81,280 B -> 2 blocks/CU

    unsigned* cnt = (unsigned*)sT1;        // 1024 u32 words (u8-packed counts)
    bf* sVemb = sAdj;                      // 32 x SR after P3 (4352 bf)
    float* sPart = (float*)(sAdj + 4352);  // 128 fp32 (P6 row partials; sAdj tail)
    bf* sS    = sT1;                       // 32 x SR (S[v][o])
    bf* sEwnT = sT1 + 4608;                // 32 x ST (ewn^T[v][node])
    float* sT2f = (float*)sT2;             // 128 x 34 fp32

    const int tid = threadIdx.x;
    const int g = blockIdx.x;
    const int wv = tid >> 6;               // 0..7
    const int lane = tid & 63;
    const int l15 = lane & 15;
    const int q = lane >> 4;
    const int kofs = q * 8;
    const int c = wv * 16 + l15;           // old-order phases' output column
    const int fq = wv * 16 + q * 4;        // new-order phases' fout base

    // ---- entry prefetches (global->VGPR; independent of all barriers) ----
    short8 Bp[4], Bn[4];
    loadB(gWb, wv, l15, kofs, Bp);                 // W_emb   (P1)
    loadB(gWb + 16384, wv, l15, kofs, Bn);         // W_gcn   (P2)
    float4 xreg[4];
    const float4* gx = (const float4*)(x + (size_t)g * 8192);
#pragma unroll
    for (int t = 0; t < 4; ++t) xreg[t] = gx[tid + t * 512];
    float4 vreg[2];
    const float4* gv = (const float4*)(vemb + (size_t)g * 4096);
#pragma unroll
    for (int t = 0; t < 2; ++t) vreg[t] = gv[tid + t * 512];
    // P6 tile: rows (wv&3)*16 + q*4 + r, v = (wv>>2)*16 + l15
    const int p6row = (wv & 3) * 16;
    const int p6v   = (wv >> 2) * 16 + l15;
    float ewreg[4];
#pragma unroll
    for (int r = 0; r < 4; ++r)
        ewreg[r] = edge_w[(size_t)g * 2048 + (p6row + q * 4 + r) * 32 + p6v];
    float bias_g = b_gcn[c];
    unsigned ecnt = min(Tot[g], (unsigned)CAP);
    unsigned ebase = (unsigned)g * CAP;

    // ---- P0a: zero counts ----
#pragma unroll
    for (int t = 0; t < 2; ++t) cnt[tid * 2 + t] = 0u;
    __syncthreads();
    // ---- P0b: build counts (LDS atomics) + stage x ----
    for (unsigned i = tid; i < ecnt; i += 512) {
        unsigned w = sorted[ebase + i];
        unsigned d = w >> 6, s = w & 63u;
        atomicAdd(&cnt[d * 16 + (s >> 2)], 1u << ((s & 3u) * 8));
    }
#pragma unroll
    for (int t = 0; t < 4; ++t) {
        int i = tid + t * 512;
        int row = i >> 5, c4 = i & 31;
        float4 w = xreg[t];
        bf4 tt;
        tt.v[0] = __float2bfloat16(w.x); tt.v[1] = __float2bfloat16(w.y);
        tt.v[2] = __float2bfloat16(w.z); tt.v[3] = __float2bfloat16(w.w);
        *(bf4*)(sRM1 + row * SR + c4 * 4) = tt;
    }
    __syncthreads();

    // ---- P0c + P1 merged (disjoint LDS: cnt/sAdj/sInv vs sRM1->sRM2) ----
    // P0c: counts -> bf16 adjacency (+self-loop) + inv=rsqrt(deg).
    // sInv/sAdj first consumed in P2/P3 (>=1 barrier later) -> safe.
    {
        int r = tid >> 3, q8 = tid & 7;
        float rs = 0.f;
#pragma unroll
        for (int t = 0; t < 2; ++t) {
            unsigned wd = cnt[r * 16 + q8 * 2 + t];
#pragma unroll
            for (int j = 0; j < 4; ++j) {
                int s = (q8 * 2 + t) * 4 + j;
                float v = (float)((wd >> (j * 8)) & 255u) + (s == r ? 1.f : 0.f);
                rs += v;
                sAdj[r * ST + s] = __float2bfloat16(v);
            }
        }
        rs += __shfl_xor(rs, 1);
        rs += __shfl_xor(rs, 2);
        rs += __shfl_xor(rs, 4);
        if (q8 == 0) sInv[r] = rsqrtf(rs);
    }
    // P1: h = x @ W_emb + b_emb -> sRM2 RM (new-order, packed bf4)
    {
        f32x4 acc[4] = {};
        mmaBA<4, 4, SR>(sRM1, 0, l15, kofs, Bp, acc);
        loadB(gWb + 2 * 16384, wv, l15, kofs, Bp);   // aff_W1 (P4)
        f32x4 b4 = *(const f32x4*)(b_emb + fq);
#pragma unroll
        for (int nt = 0; nt < 4; ++nt) {
            bf4 tv;
#pragma unroll
            for (int r = 0; r < 4; ++r) tv.v[r] = __float2bfloat16(acc[nt][r] + b4[r]);
            *(bf4*)(sRM2 + (nt * 16 + l15) * SR + fq) = tv;
        }
    }
    __syncthreads();

    // ---- P2: hws^T = (h @ W_gcn) * inv[row] -> sT1 (old-order, packed T) ----
    {
        f32x4 acc[4] = {};
        mmaAB<4, 4, SR>(sRM2, 0, l15, kofs, Bn, acc);
        loadB(gWb + 3 * 16384, wv, l15, kofs, Bn);   // aff_W2 (P5)
#pragma unroll
        for (int m = 0; m < 4; ++m) {
            bf4 tv;
#pragma unroll
            for (int r = 0; r < 4; ++r)
                tv.v[r] = __float2bfloat16(acc[m][r] * sInv[m * 16 + q * 4 + r]);
            *(bf4*)(sT1 + c * ST + m * 16 + q * 4) = tv;
        }
    }
    __syncthreads();

    // ---- P3: h_gcn = relu(inv[d]*(A' @ hws) + b_gcn) -> sRM1 RM + sT2 T ----
    {
        f32x4 acc[4] = {};
        mmaABlds<4, 2, ST, ST>(sAdj, 0, sT1, wv * 16, l15, kofs, acc);
#pragma unroll
        for (int m = 0; m < 4; ++m) {
            bf4 tv;
#pragma unroll
            for (int r = 0; r < 4; ++r) {
                float v = fmaxf(acc[m][r] * sInv[m * 16 + q * 4 + r] + bias_g, 0.f);
                sRM1[(m * 16 + q * 4 + r) * SR + c] = __float2bfloat16(v);
                tv.v[r] = __float2bfloat16(v);
            }
            *(bf4*)(sT2 + c * ST + m * 16 + q * 4) = tv;
        }
    }
    __syncthreads();

    // ---- P4: affh = relu(h_gcn @ aff_W1 + aff_b1) -> sRM2 RM ; vemb -> LDS ----
    {
#pragma unroll
        for (int t = 0; t < 2; ++t) {
            int i = tid + t * 512;
            int v = i >> 5, o4 = i & 31;
            float4 w = vreg[t];
            bf4 tt;
            tt.v[0] = __float2bfloat16(w.x); tt.v[1] = __float2bfloat16(w.y);
            tt.v[2] = __float2bfloat16(w.z); tt.v[3] = __float2bfloat16(w.w);
            *(bf4*)(sVemb + v * SR + o4 * 4) = tt;
        }
        f32x4 acc[4] = {};
        mmaBA<4, 4, SR>(sRM1, 0, l15, kofs, Bp, acc);
        loadB(gWb + 4 * 16384, wv, l15, kofs, Bp);   // vn_W1 (P8)
        f32x4 b4 = *(const f32x4*)(aff_b1 + fq);
#pragma unroll
        for (int nt = 0; nt < 4; ++nt) {
            bf4 tv;
#pragma unroll
            for (int r = 0; r < 4; ++r)
                tv.v[r] = __float2bfloat16(fmaxf(acc[nt][r] + b4[r], 0.f));
            *(bf4*)(sRM2 + (nt * 16 + l15) * SR + fq) = tv;
        }
    }
    __syncthreads();

    // ---- P5: S[v][o] = sum_j vemb[v][j]*aff_W2[o][j] -> sS ; batt ----
    {
        f32x4 acc[2] = {};
        mmaBA<2, 4, SR>(sVemb, 0, l15, kofs, Bn, acc);
        loadB(gWb + 5 * 16384, wv, l15, kofs, Bn);   // vn_W2 (P9)
#pragma unroll
        for (int nt = 0; nt < 2; ++nt) {
            bf4 tv;
#pragma unroll
            for (int r = 0; r < 4; ++r) tv.v[r] = __float2bfloat16(acc[nt][r]);
            *(bf4*)(sS + (nt * 16 + l15) * SR + fq) = tv;
        }
        if (tid < 256) {
            int v = tid >> 3, sg = tid & 7;
            float s = 0.f;
            const bf* pv = sVemb + v * SR + sg * 16;
            const float* pb = aff_b2 + sg * 16;
#pragma unroll
            for (int o = 0; o < 16; ++o) s += pb[o] * __bfloat162float(pv[o]);
            s += __shfl_xor(s, 1); s += __shfl_xor(s, 2); s += __shfl_xor(s, 4);
            if (sg == 0) sBatt[v] = s;
        }
    }
    __syncthreads();

    // ---- P6: att -> sigmoid gate -> row-normalize -> sEwnT[v][node] ----
    {
        f32x4 acc = {};
        const int hv = wv >> 2;
#pragma unroll
        for (int ks = 0; ks < 4; ++ks) {
            short8 bb = *(const short8*)(sS + (hv * 16 + l15) * SR + ks * 32 + kofs);
            short8 a  = *(const short8*)(sRM2 + (p6row + l15) * SR + ks * 32 + kofs);
            acc = __builtin_amdgcn_mfma_f32_16x16x32_bf16(a, bb, acc, 0, 0, 0);
        }
        const float sc = 0.08838834764831845f;   // 1/sqrt(128)
        float bt = sBatt[p6v];
        float e[4];
#pragma unroll
        for (int r = 0; r < 4; ++r) {
            float att = (acc[r] + bt) * sc;
            e[r] = ewreg[r] * (1.f + 1.f / (1.f + __expf(-att)));
            float rs = e[r];
            rs += __shfl_xor(rs, 1); rs += __shfl_xor(rs, 2);
            rs += __shfl_xor(rs, 4); rs += __shfl_xor(rs, 8);
            if (l15 == 0) sPart[hv * 64 + p6row + q * 4 + r] = rs;
        }
        __syncthreads();
        bf4 tv;
#pragma unroll
        for (int r = 0; r < 4; ++r) {
            float rs = sPart[p6row + q * 4 + r] + sPart[64 + p6row + q * 4 + r];
            tv.v[r] = __float2bfloat16(e[r] / rs);
        }
        *(bf4*)(sEwnT + (hv * 16 + l15) * ST + p6row + q * 4) = tv;
    }
    __syncthreads();

    // ---- P7: vn = ewn^T @ h_gcn -> sRM1 rows 0..31 (A=h_gcnT, B=ewnT; packed) ----
    {
        f32x4 acc[2] = {};
#pragma unroll
        for (int ks = 0; ks < 2; ++ks) {
            short8 af = *(const short8*)(sT2 + (wv * 16 + l15) * ST + ks * 32 + kofs);
            short8 b0 = *(const short8*)(sEwnT + l15 * ST + ks * 32 + kofs);
            short8 b1 = *(const short8*)(sEwnT + (16 + l15) * ST + ks * 32 + kofs);
            acc[0] = __builtin_amdgcn_mfma_f32_16x16x32_bf16(af, b0, acc[0], 0, 0, 0);
            acc[1] = __builtin_amdgcn_mfma_f32_16x16x32_bf16(af, b1, acc[1], 0, 0, 0);
        }
#pragma unroll
        for (int nt = 0; nt < 2; ++nt) {
            bf4 tv;
#pragma unroll
            for (int r = 0; r < 4; ++r) tv.v[r] = __float2bfloat16(acc[nt][r]);
            *(bf4*)(sRM1 + (nt * 16 + l15) * SR + fq) = tv;
        }
    }
    __syncthreads();

    // ---- P8: z1 = relu(vn @ vn_W1 + vn_b1) -> sRM1 rows 32..63 (new-order) ----
    {
        f32x4 acc[2] = {};
        mmaBA<2, 4, SR>(sRM1, 0, l15, kofs, Bp, acc);
        f32x4 b4 = *(const f32x4*)(vn_b1 + fq);
#pragma unroll
        for (int nt = 0; nt < 2; ++nt) {
            bf4 tv;
#pragma unroll
            for (int r = 0; r < 4; ++r)
                tv.v[r] = __float2bfloat16(fmaxf(acc[nt][r] + b4[r], 0.f));
            *(bf4*)(sRM1 + (32 + nt * 16 + l15) * SR + fq) = tv;
        }
    }
    __syncthreads();

    // ---- P9: vn2 = z1 @ vn_W2 + vn_b2 -> sT2f[feat][v] fp32 (old-order) ----
    {
        float bias_v2 = vn_b2[c];
        f32x4 acc[2] = {};
        mmaAB<2, 4, SR>(sRM1 + 32 * SR, 0, l15, kofs, Bn, acc);
#pragma unroll
        for (int m = 0; m < 2; ++m)
#pragma unroll
            for (int r = 0; r < 4; ++r)
                sT2f[c * 34 + m * 16 + q * 4 + r] = acc[m][r] + bias_v2;
    }
    __syncthreads();

    // ---- P10: gf = mean over V -> LDS (sRM2 reused as fp32 scratch) ----
    float* sF = (float*)sRM2;    // [0:128)=gf, [128:640)=partials, [640:768)=z1
    if (tid < 128) {
        float s = 0.f;
#pragma unroll
        for (int v = 0; v < 32; ++v) s += sT2f[tid * 34 + v];
        sF[tid] = s * 0.03125f;
    }
    __syncthreads();

    // ---- P11: z1 = relu(gf @ mlp_W1 + mlp_b1) (fp32, split-K over 4) ----
    {
        int o = tid & 127, hh = tid >> 7;            // hh = 0..3
        const float* w = mlp_W1 + (size_t)(hh * 32) * 128 + o;
        float a = 0.f;
#pragma unroll 8
        for (int k = 0; k < 32; ++k) a = fmaf(sF[hh * 32 + k], w[k * 128], a);
        sF[128 + hh * 128 + o] = a;
    }
    __syncthreads();
    if (tid < 128)
        sF[640 + tid] = fmaxf(sF[128 + tid] + sF[256 + tid] + sF[384 + tid]
                              + sF[512 + tid] + mlp_b1[tid], 0.f);
    __syncthreads();

    // ---- P12: out = z1 @ mlp_W2 + mlp_b2 ----
    if (tid < 80) {
        int oo = tid >> 3, jg = tid & 7;
        float p = 0.f;
#pragma unroll
        for (int t2 = 0; t2 < 16; ++t2) {
            int j = jg * 16 + t2;
            p = fmaf(sF[640 + j], mlp_W2[j * 10 + oo], p);
        }
        p += __shfl_xor(p, 1); p += __shfl_xor(p, 2); p += __shfl_xor(p, 4);
        if (jg == 0) out[g * 10 + oo] = p + mlp_b2[oo];
    }
}

extern "C" void kernel_launch(void* const* d_in, const int* in_sizes, int n_in,
                              void* d_out, int out_size, void* d_ws, size_t ws_size,
                              hipStream_t stream)
{
    const float* x       = (const float*)d_in[0];
    const int*   ei      = (const int*)  d_in[1];
    // d_in[2] = batch (unused)
    const float* edge_w  = (const float*)d_in[3];
    const float* vemb    = (const float*)d_in[4];
    const float* W_emb   = (const float*)d_in[5];
    const float* b_emb   = (const float*)d_in[6];
    const float* W_gcn   = (const float*)d_in[7];
    const float* b_gcn   = (const float*)d_in[8];
    const float* aff_W1  = (const float*)d_in[9];
    const float* aff_b1  = (const float*)d_in[10];
    const float* aff_W2  = (const float*)d_in[11];
    const float* aff_b2  = (const float*)d_in[12];
    const float* vn_W1   = (const float*)d_in[13];
    const float* vn_b1   = (const float*)d_in[14];
    const float* vn_W2   = (const float*)d_in[15];
    const float* vn_b2   = (const float*)d_in[16];
    const float* mlp_W1  = (const float*)d_in[17];
    const float* mlp_b1  = (const float*)d_in[18];
    const float* mlp_W2  = (const float*)d_in[19];
    const float* mlp_b2  = (const float*)d_in[20];

    char* ws = (char*)d_ws;
    unsigned short* sorted = (unsigned short*)ws;               // 4 MB (1024*2048 u16)
    unsigned* H    = (unsigned*)(ws + (4u << 20));              // 1 MB (256*1024 u32)
    unsigned* Tot  = (unsigned*)(ws + (5u << 20));              // 4 KB
    bf*       gWb  = (bf*)      (ws + (5u << 20) + 65536);      // 192 KB

    edge_hist  <<<dim3(256), dim3(256), 0, stream>>>(ei, H);
    scan_conv  <<<dim3(320), dim3(256), 0, stream>>>(
        H, Tot, W_emb, W_gcn, aff_W1, aff_W2, vn_W1, vn_W2, gWb);
    edge_scatter<<<dim3(256),dim3(256), 0, stream>>>(ei, H, sorted);
    fused_graph<<<dim3(1024), dim3(512), 0, stream>>>(
        x, edge_w, vemb, gWb, b_emb, b_gcn, aff_b1, aff_b2,
        vn_b1, vn_b2, mlp_W1, mlp_b1, mlp_W2, mlp_b2,
        sorted, Tot, (float*)d_out);
}